// Round 17
// baseline (110.478 us; speedup 1.0000x reference)
//
#include <hip/hip_runtime.h>

#define DM 1024
#define NH 16
#define DK 64
#define BB 2
#define SS 2048

typedef unsigned short u16;
typedef unsigned int   u32;
typedef __bf16 bf16x8 __attribute__((ext_vector_type(8)));
typedef float  f32x4  __attribute__((ext_vector_type(4)));
typedef float  f32x16 __attribute__((ext_vector_type(16)));

__device__ __forceinline__ u16 f2bf(float f){
  u32 u = __float_as_uint(f);
  u32 r = (u + 0x7FFFu + ((u >> 16) & 1u)) >> 16;   // RNE
  return (u16)r;
}
__device__ __forceinline__ float bf2f(u16 v){ return __uint_as_float(((u32)v) << 16); }

__device__ __forceinline__ u32 cvtpk(float lo, float hi){
  u32 r;
  asm volatile("v_cvt_pk_bf16_f32 %0, %1, %2" : "=v"(r) : "v"(lo), "v"(hi));
  return r;
}

__device__ __forceinline__ void gl16(const void* g, void* l){
  __builtin_amdgcn_global_load_lds((const __attribute__((address_space(1))) u32*)g,
                                   (__attribute__((address_space(3))) u32*)l, 16, 0, 0);
}
__device__ __forceinline__ f32x16 mfma32(bf16x8 a, bf16x8 b, f32x16 c){
  return __builtin_amdgcn_mfma_f32_32x32x16_bf16(a, b, c, 0, 0, 0);
}

// ------- merged cast (x + 4 weights) + RoPE trig-table fill (tail blocks) -------
__global__ void k_cast(const float* __restrict__ x,  const float* __restrict__ wq,
                       const float* __restrict__ wk, const float* __restrict__ wv,
                       const float* __restrict__ wo, u16* __restrict__ xb,
                       u16* __restrict__ wb, float* __restrict__ tab){
  if (blockIdx.x >= 8192){
    int e = (blockIdx.x - 8192)*256 + threadIdx.x;
    int p = e >> 5, j = e & 31;
    float s, c;
    sincosf((float)p * exp2f(-0.4152410118609203f * (float)j), &s, &c);
    float2 v; v.x = c; v.y = s;
    *(float2*)(tab + e*2) = v;
    return;
  }
  int e = blockIdx.x*1024 + threadIdx.x*4;
  int r = e >> 20;
  const float* s; u16* d; int local;
  if (r < 4){ s = x; d = xb; local = e; }
  else {
    const float* ws[4] = {wq, wk, wv, wo};
    int w = r - 4;
    local = e & 0xFFFFF;
    s = ws[w]; d = wb + ((size_t)w << 20);
  }
  float4 v = *(const float4*)(s + local);
  uint2 t; t.x = cvtpk(v.x, v.y); t.y = cvtpk(v.z, v.w);
  *(uint2*)(d + local) = t;
}

// XCD-chunked bijective block swizzle (nwg % 8 == 0)
__device__ __forceinline__ int xcd_swz(int lin, int nwg){
  return (lin & 7) * (nwg >> 3) + (lin >> 3);
}

// ---------------- GEMM core R17: 32x32 MFMA, 16-slot swizzle, R10 skeleton ------
// LDS tile: [128 rows][128B] (row = A 64B || B 64B), read-swizzle
// addr = (row*128 + c) ^ ((row&15)<<4)  (R15-measured conflict-clean for 32-row
// b128 reads). Stage decodes the INVERSE analytically (bits >=8 give row bits 1-3
// -> mask bits 5-7 -> bit7 -> row bit 0). Each b128 frag feeds a 32x32 MFMA ->
// 8 ds_read_b128 per K-step/wave (was 16). Loop: BK=32, 3 buffers, vmcnt(4).
// SWAP=true: C reg r -> n (rowfn), lane&31 -> m. SWAP=false: reg r -> m, lane&31 -> n.
// rowfn(r,hh) = (r&3) + 8*(r>>2) + 4*hh  [HW-verified m74/m101, R12/R15].
template<bool SWAP>
__device__ __forceinline__ void gemm_core(const u16* __restrict__ A, const u16* __restrict__ Bw,
                                          u16* S, f32x16 (&acc)[2][2], int m0, int n0){
  const int tid = threadIdx.x, lane = tid & 63, wid = tid >> 6;
  const int wm = (wid >> 1) * 64, wn = (wid & 1) * 64;
  const int qi = lane & 31, hh = lane >> 5;

  #define STAGE_G(buf, k0)                                                       \
    _Pragma("unroll")                                                            \
    for (int i = 0; i < 4; i++){                                                 \
      int L = i*4096 + tid*16;                                                   \
      int rb = (L >> 8) & 7;                   /* row bits 1..3 */               \
      int b7 = ((L >> 7) ^ (rb >> 2)) & 1;     /* row bit 0 */                   \
      int row = ((L >> 7) & 126) | b7;                                           \
      int col = (L ^ ((row & 15) << 4)) & 127;                                   \
      const u16* src = (col < 64)                                                \
          ? (A  + (size_t)(m0 + row)*DM + (k0) + (col >> 1))                     \
          : (Bw + (size_t)(n0 + row)*DM + (k0) + ((col - 64) >> 1));             \
      gl16(src, (char*)(buf) + L);                                               \
    }

  #define COMPUTE_T(buf)                                                         \
    {                                                                            \
      bf16x8 af[2][2], bfr[2][2];                                                \
      _Pragma("unroll")                                                          \
      for (int mi = 0; mi < 2; mi++){                                            \
        int r = wm + mi*32 + qi;                                                 \
        int base = r*128;                                                        \
        int msk = (r & 15) << 4;                                                 \
        af[mi][0] = *(const bf16x8*)((char*)(buf) + ((base + hh*16) ^ msk));     \
        af[mi][1] = *(const bf16x8*)((char*)(buf) + ((base + 32 + hh*16) ^ msk));\
      }                                                                          \
      _Pragma("unroll")                                                          \
      for (int ni = 0; ni < 2; ni++){                                            \
        int r = wn + ni*32 + qi;                                                 \
        int base = r*128 + 64;                                                   \
        int msk = (r & 15) << 4;                                                 \
        bfr[ni][0] = *(const bf16x8*)((char*)(buf) + ((base + hh*16) ^ msk));    \
        bfr[ni][1] = *(const bf16x8*)((char*)(buf) + ((base + 32 + hh*16) ^ msk));\
      }                                                                          \
      __builtin_amdgcn_s_setprio(1);                                             \
      _Pragma("unroll")                                                          \
      for (int mi = 0; mi < 2; mi++)                                             \
        _Pragma("unroll")                                                        \
        for (int ni = 0; ni < 2; ni++){                                          \
          if (SWAP){                                                             \
            acc[mi][ni] = mfma32(bfr[ni][0], af[mi][0], acc[mi][ni]);            \
            acc[mi][ni] = mfma32(bfr[ni][1], af[mi][1], acc[mi][ni]);            \
          } else {                                                               \
            acc[mi][ni] = mfma32(af[mi][0], bfr[ni][0], acc[mi][ni]);            \
            acc[mi][ni] = mfma32(af[mi][1], bfr[ni][1], acc[mi][ni]);            \
          }                                                                      \
        }                                                                        \
      __builtin_amdgcn_s_setprio(0);                                             \
    }

  char* b0 = (char*)S;
  char* b1 = (char*)S + 16384;
  char* b2 = (char*)S + 32768;

  STAGE_G(b0, 0);
  STAGE_G(b1, 32);

  #pragma unroll 3
  for (int t = 0; t < 30; t++){
    asm volatile("s_waitcnt vmcnt(4)" ::: "memory");   // stage(t) done, (t+1) in flight
    __builtin_amdgcn_s_barrier();
    STAGE_G(b2, (t+2)*32);                             // depth-2 prefetch
    COMPUTE_T(b0);
    char* tmp = b0; b0 = b1; b1 = b2; b2 = tmp;
  }
  asm volatile("s_waitcnt vmcnt(4)" ::: "memory");
  __builtin_amdgcn_s_barrier();
  COMPUTE_T(b0);
  { char* tmp = b0; b0 = b1; b1 = b2; b2 = tmp; }
  asm volatile("s_waitcnt vmcnt(0)" ::: "memory");
  __builtin_amdgcn_s_barrier();
  COMPUTE_T(b0);

  #undef STAGE_G
  #undef COMPUTE_T
}

// QKV GEMM. z=0/1: fused RoPE (trig table), row-major out. z=2: V transposed.
// SWAP layout: n = wn0 + ni*32 + 8*(r>>2) + 4*hh + (r&3);  m = wm0 + mi*32 + qi.
__global__ __launch_bounds__(256) void k_gemm_qkv(const u16* __restrict__ xb, const u16* __restrict__ Wb,
                                                  u16* __restrict__ Qb, u16* __restrict__ Kb,
                                                  u16* __restrict__ Vt_g, const int* __restrict__ pos,
                                                  const float* __restrict__ tab){
  __shared__ __align__(16) u16 S[3*8192];
  int lin = (int)blockIdx.x + 8*((int)blockIdx.y + 32*(int)blockIdx.z);
  lin = xcd_swz(lin, 768);
  const int bx = lin & 7, by = (lin >> 3) & 31, z = lin >> 8;
  const int m0 = by * 128, n0 = bx * 128;

  const u16* Bw = Wb + ((size_t)z << 20);
  f32x16 acc[2][2] = {};
  gemm_core<true>(xb, Bw, S, acc, m0, n0);
  const int lane = threadIdx.x & 63, wid = threadIdx.x >> 6;
  const int wm0 = m0 + (wid >> 1)*64, wn0 = n0 + (wid & 1)*64;
  const int qi = lane & 31, hh = lane >> 5;

  if (z == 2){
    // V^T[b][h*64+d][s]: feature n varies with (ni, rq, hh, j), token from m.
    #pragma unroll
    for (int mi = 0; mi < 2; mi++){
      const int mrow = wm0 + mi*32 + qi;
      const int bq = mrow >> 11, sq = mrow & (SS-1);
      u16* vt = Vt_g + ((size_t)bq*NH*DK)*SS + sq;
      #pragma unroll
      for (int ni = 0; ni < 2; ni++)
        #pragma unroll
        for (int rq = 0; rq < 4; rq++){
          const int nb = wn0 + ni*32 + rq*8 + hh*4;
          #pragma unroll
          for (int j = 0; j < 4; j++)
            vt[(size_t)(nb + j)*SS] = f2bf(acc[mi][ni][rq*4 + j]);
        }
    }
    return;
  }

  u16* C = (z == 0) ? Qb : Kb;
  const float4* tab4 = (const float4*)tab;
  #pragma unroll
  for (int mi = 0; mi < 2; mi++){
    const int mrow = wm0 + mi*32 + qi;
    const int p = pos[mrow & (SS-1)];
    #pragma unroll
    for (int ni = 0; ni < 2; ni++)
      #pragma unroll
      for (int rq = 0; rq < 4; rq++){
        const int nb = wn0 + ni*32 + rq*8 + hh*4;    // 4 consecutive n, mult of 4
        float o0 = acc[mi][ni][rq*4+0], o1 = acc[mi][ni][rq*4+1];
        float o2 = acc[mi][ni][rq*4+2], o3 = acc[mi][ni][rq*4+3];
        int j0 = (nb >> 1) & 31;
        float4 cs = tab4[p*16 + (j0 >> 1)];
        float t0 = o0*cs.x - o1*cs.y, t1 = o0*cs.y + o1*cs.x;
        o0 = t0; o1 = t1;
        t0 = o2*cs.z - o3*cs.w; t1 = o2*cs.w + o3*cs.z;
        o2 = t0; o3 = t1;
        uint2 w; w.x = cvtpk(o0, o1); w.y = cvtpk(o2, o3);
        *(uint2*)(C + (size_t)mrow*DM + nb) = w;
      }
  }
}

// out GEMM (SWAP=false): m = wm0 + mi*32 + 8*(r>>2)+4*hh+(r&3); n = wn0 + ni*32 + qi.
__global__ __launch_bounds__(256) void k_gemm_out(const u16* __restrict__ AO, const u16* __restrict__ Wo,
                                                  float* __restrict__ Co){
  __shared__ __align__(16) u16 S[3*8192];
  int lin = (int)blockIdx.x + 8*(int)blockIdx.y;
  lin = xcd_swz(lin, 256);
  const int bx = lin & 7, by = lin >> 3;
  const int m0 = by * 128, n0 = bx * 128;

  f32x16 acc[2][2] = {};
  gemm_core<false>(AO, Wo, S, acc, m0, n0);
  const int lane = threadIdx.x & 63, wid = threadIdx.x >> 6;
  const int wm0 = m0 + (wid >> 1)*64, wn0 = n0 + (wid & 1)*64;
  const int qi = lane & 31, hh = lane >> 5;
  #pragma unroll
  for (int mi = 0; mi < 2; mi++)
    #pragma unroll
    for (int ni = 0; ni < 2; ni++)
      #pragma unroll
      for (int r = 0; r < 16; r++){
        int m = wm0 + mi*32 + (r & 3) + 8*(r >> 2) + 4*hh;
        int n = wn0 + ni*32 + qi;
        Co[(size_t)m*DM + n] = acc[mi][ni][r];
      }
}

// ---------------- flash attention (R16, verified 47.5us) ----------------
__global__ __launch_bounds__(512, 4) void k_attn(const u16* __restrict__ Q, const u16* __restrict__ K,
                                                 const u16* __restrict__ Vt_g, u16* __restrict__ AO){
  __shared__ __align__(16) u16 Ks[4][64*64];
  __shared__ __align__(16) u16 Vt[4][64*64];
  const int tid = threadIdx.x, lane = tid & 63, wid = tid >> 6;
  const int b = blockIdx.z, h = blockIdx.y;
  const int qb = b ? (15 - (int)blockIdx.x) : (int)blockIdx.x;
  const int strip = wid & 3, g = wid >> 2;
  const int qw = qb*128 + strip*32;
  const size_t base = ((size_t)b*SS)*DM + (size_t)h*DK;
  const size_t vtb  = ((size_t)b*NH + h)*DK*SS;
  const int qi = lane & 31, hh = lane >> 5;
  const int NI = qb + 1;
  const float SC = 0.18033688011112042f;
  const float THR = 8.0f / SC;
  const int qm15 = (qi & 15) << 4;

  const u16* qptr = Q + base + (size_t)(qw + qi)*DM + hh*8;
  bf16x8 qf0 = *(const bf16x8*)(qptr);
  bf16x8 qf1 = *(const bf16x8*)(qptr + 16);
  bf16x8 qf2 = *(const bf16x8*)(qptr + 32);
  bf16x8 qf3 = *(const bf16x8*)(qptr + 48);

  const int L = tid*16;
  const int Lm = ((L >> 3) & 0xF0) ^ ((L >> 6) & 0x10);
  const int A_ = L ^ Lm;
  const int srow = A_ >> 7;
  const int scol = (A_ & 127) >> 1;

  #define STAGE1(bi, t)                                                          \
    {                                                                             \
      const int kn0_ = (t)*64;                                                    \
      gl16(K    + base + (size_t)(kn0_ + srow)*DM + scol, (char*)Ks[bi] + L);      \
      gl16(Vt_g + vtb  + (size_t)srow*SS + kn0_ + scol, (char*)Vt[bi] + L);        \
    }

  STAGE1(0, 0); STAGE1(1, 1);
  if (NI > 1){
    STAGE1(2, 2); STAGE1(3, 3);
    asm volatile("s_waitcnt vmcnt(4)" ::: "memory");
  } else {
    asm volatile("s_waitcnt vmcnt(0)" ::: "memory");
  }
  __builtin_amdgcn_s_barrier();

  f32x16 oacc0 = {}, oacc1 = {};
  float m = -3e38f, lsum = 0.f;

  for (int k = 0; k < NI; k++){
    const int t = 2*k + g;
    const int kv0 = t*64;
    const int bsel = ((k & 1) << 1) | g;
    const char* kb = (const char*)Ks[bsel];
    const char* vb = (const char*)Vt[bsel];

    if (kv0 <= qw + 31){
      #pragma unroll
      for (int H = 0; H < 2; H++){
        f32x16 sf = {};
        __builtin_amdgcn_s_setprio(1);
        #pragma unroll
        for (int kc = 0; kc < 4; kc++){
          const int a0 = (qi*128 + kc*32 + hh*16) ^ qm15;
          bf16x8 kf = *(const bf16x8*)(kb + a0 + H*4096);
          bf16x8 qf = (kc == 0) ? qf0 : (kc == 1) ? qf1 : (kc == 2) ? qf2 : qf3;
          sf = mfma32(kf, qf, sf);
        }
        __builtin_amdgcn_s_setprio(0);

        if (kv0 + 32*H + 31 > qw){
          const int qa = qw + qi;
          #pragma unroll
          for (int r = 0; r < 16; r++){
            int rowoff = 32*H + (r & 3) + 8*(r >> 2) + 4*hh;
            sf[r] = (kv0 + rowoff <= qa) ? sf[r] : -3e38f;
          }
        }

        float t0 = fmaxf(fmaxf(sf[0],  sf[1]),  sf[2]);
        float t1 = fmaxf(fmaxf(sf[3],  sf[4]),  sf[5]);
        float t2 = fmaxf(fmaxf(sf[6],  sf[7]),  sf[8]);
        float t3 = fmaxf(fmaxf(sf[9],  sf[10]), sf[11]);
        float t4 = fmaxf(fmaxf(sf[12], sf[13]), sf[14]);
        float mx = fmaxf(fmaxf(fmaxf(t0, t1), t2), fmaxf(fmaxf(t3, t4), sf[15]));

        if (!__all(mx <= m + THR)){
          mx = fmaxf(mx, __shfl_xor(mx, 32));
          const float mn = fmaxf(m, mx);
          const float alpha = exp2f((m - mn)*SC);
          oacc0 *= alpha; oacc1 *= alpha; lsum *= alpha;
          m = mn;
        }

        const float nms = -m*SC;
        float psum = 0.f;
        #pragma unroll
        for (int r = 0; r < 16; r++){
          sf[r] = exp2f(fmaf(sf[r], SC, nms));
          psum += sf[r];
        }
        lsum += psum;

        __builtin_amdgcn_s_setprio(1);
        #pragma unroll
        for (int TT = 0; TT < 2; TT++){
          u32 w0 = cvtpk(sf[8*TT+0], sf[8*TT+1]);
          u32 w1 = cvtpk(sf[8*TT+2], sf[8*TT+3]);
          u32 w2 = cvtpk(sf[8*TT+4], sf[8*TT+5]);
          u32 w3 = cvtpk(sf[8*TT+6], sf[8*TT+7]);
          asm volatile("v_permlane32_swap_b32 %0, %1" : "+v"(w0), "+v"(w2));
          asm volatile("v_permlane32_swap_b32 %0, %1" : "+v"(w1), "+v"(w3));
          u32 pw[4] = {w0, w1, w2, w3};
          bf16x8 pf;
          __builtin_memcpy(&pf, pw, 16);
          const int av = (qi*128 + (2*H + TT)*32 + hh*16) ^ qm15;
          bf16x8 vfa = *(const bf16x8*)(vb + av);
          bf16x8 vfb = *(const bf16x8*)(vb + av + 4096);
          oacc0 = mfma32(vfa, pf, oacc0);
          oacc1 = mfma32(vfb, pf, oacc1);
        }
        __builtin_amdgcn_s_setprio(0);
      }
    }

    __builtin_amdgcn_s_barrier();
    if (k + 2 < NI){
      STAGE1(((k & 1) << 1) | 0, 2*k + 4);
      STAGE1(((k & 1) << 1) | 1, 2*k + 5);
    }
    if (k + 1 < NI){
      if (k + 2 < NI) asm volatile("s_waitcnt vmcnt(4)" ::: "memory");
      else            asm volatile("s_waitcnt vmcnt(0)" ::: "memory");
      __builtin_amdgcn_s_barrier();
    }
  }
  #undef STAGE1

  __builtin_amdgcn_s_barrier();
  float2* exv  = (float2*)Ks;
  float2* exml = (float2*)((char*)Vt + 16384);
  if (g == 1){
    int idx = (wid - 4)*64 + lane;
    #pragma unroll
    for (int e = 0; e < 8; e++){
      float2 v0; v0.x = oacc0[2*e]; v0.y = oacc0[2*e+1];
      float2 v1; v1.x = oacc1[2*e]; v1.y = oacc1[2*e+1];
      exv[e*256 + idx] = v0;
      exv[(8+e)*256 + idx] = v1;
    }
    float2 ml; ml.x = m; ml.y = lsum;
    exml[idx] = ml;
  }
  __builtin_amdgcn_s_barrier();
  if (g == 1) return;

  {
    int idx = wid*64 + lane;
    float2 ml = exml[idx];
    const float mm = fmaxf(m, ml.x);
    const float aA = exp2f((m - mm)*SC);
    const float aB = exp2f((ml.x - mm)*SC);
    lsum = lsum*aA + ml.y*aB;
    #pragma unroll
    for (int e = 0; e < 8; e++){
      float2 v0 = exv[e*256 + idx];
      float2 v1 = exv[(8+e)*256 + idx];
      oacc0[2*e]   = oacc0[2*e]*aA   + v0.x*aB;
      oacc0[2*e+1] = oacc0[2*e+1]*aA + v0.y*aB;
      oacc1[2*e]   = oacc1[2*e]*aA   + v1.x*aB;
      oacc1[2*e+1] = oacc1[2*e+1]*aA + v1.y*aB;
    }
  }
  lsum += __shfl_xor(lsum, 32);
  const float rl = 1.0f / lsum;

  char* sc = (char*)Vt[0] + wid*4096;
  #pragma unroll
  for (int w = 0; w < 8; w++){
    const int pb = (w & 1)*2 + (w >> 1)*8;
    const int db0 = 4*hh + pb;
    const int db1 = 32 + 4*hh + pb;
    *(u32*)(sc + ((qi*128 + db0*2) ^ ((qi & 7) << 4))) = cvtpk(oacc0[2*w]*rl, oacc0[2*w+1]*rl);
    *(u32*)(sc + ((qi*128 + db1*2) ^ ((qi & 7) << 4))) = cvtpk(oacc1[2*w]*rl, oacc1[2*w+1]*rl);
  }
  #pragma unroll
  for (int pass = 0; pass < 4; pass++){
    int qr = pass*8 + (lane >> 3);
    int d0 = (lane & 7)*8;
    bf16x8 row = *(const bf16x8*)(sc + ((qr*128 + d0*2) ^ ((qr & 7) << 4)));
    *(bf16x8*)(AO + base + (size_t)(qw + qr)*DM + d0) = row;
  }
}

// ---------------- launch ----------------
extern "C" void kernel_launch(void* const* d_in, const int* in_sizes, int n_in,
                              void* d_out, int out_size, void* d_ws, size_t ws_size,
                              hipStream_t stream){
  const float* x   = (const float*)d_in[0];
  const float* Wq  = (const float*)d_in[1];
  const float* Wk  = (const float*)d_in[2];
  const float* Wv  = (const float*)d_in[3];
  const float* Wo  = (const float*)d_in[4];
  const int*   pos = (const int*)d_in[5];
  float* out = (float*)d_out;

  const size_t NEED = ((size_t)41 << 20);
  if (ws_size < NEED){
    hipMemsetAsync(d_out, 0x7f, (size_t)out_size * sizeof(float), stream);
    return;
  }

  char* ws = (char*)d_ws;
  u16* xb   = (u16*)(ws);
  u16* Wb   = (u16*)(ws + ((size_t)8  << 20));
  u16* Qb   = (u16*)(ws + ((size_t)16 << 20));
  u16* Kb   = (u16*)(ws + ((size_t)24 << 20));
  u16* Vt   = (u16*)(ws + ((size_t)32 << 20));
  float* tab = (float*)(ws + ((size_t)40 << 20));
  u16* AO = xb;

  k_cast<<<8448, 256, 0, stream>>>(x, Wq, Wk, Wv, Wo, xb, Wb, tab);
  k_gemm_qkv<<<dim3(8, 32, 3), 256, 0, stream>>>(xb, Wb, Qb, Kb, Vt, pos, tab);
  k_attn<<<dim3(16, 16, 2), 512, 0, stream>>>(Qb, Kb, Vt, AO);
  k_gemm_out<<<dim3(8, 32), 256, 0, stream>>>(AO, Wb + ((size_t)3 << 20), out);
}

// Round 18
// 109.330 us; speedup vs baseline: 1.0105x; 1.0105x over previous
//
#include <hip/hip_runtime.h>

#define DM 1024
#define NH 16
#define DK 64
#define BB 2
#define SS 2048

typedef unsigned short u16;
typedef unsigned int   u32;
typedef __bf16 bf16x8 __attribute__((ext_vector_type(8)));
typedef float  f32x4  __attribute__((ext_vector_type(4)));
typedef float  f32x16 __attribute__((ext_vector_type(16)));

__device__ __forceinline__ u16 f2bf(float f){
  u32 u = __float_as_uint(f);
  u32 r = (u + 0x7FFFu + ((u >> 16) & 1u)) >> 16;   // RNE
  return (u16)r;
}
__device__ __forceinline__ float bf2f(u16 v){ return __uint_as_float(((u32)v) << 16); }

__device__ __forceinline__ u32 cvtpk(float lo, float hi){
  u32 r;
  asm volatile("v_cvt_pk_bf16_f32 %0, %1, %2" : "=v"(r) : "v"(lo), "v"(hi));
  return r;
}

__device__ __forceinline__ void gl16(const void* g, void* l){
  __builtin_amdgcn_global_load_lds((const __attribute__((address_space(1))) u32*)g,
                                   (__attribute__((address_space(3))) u32*)l, 16, 0, 0);
}
__device__ __forceinline__ f32x4 mfma16(bf16x8 a, bf16x8 b, f32x4 c){
  return __builtin_amdgcn_mfma_f32_16x16x32_bf16(a, b, c, 0, 0, 0);
}
__device__ __forceinline__ f32x16 mfma32(bf16x8 a, bf16x8 b, f32x16 c){
  return __builtin_amdgcn_mfma_f32_32x32x16_bf16(a, b, c, 0, 0, 0);
}

// ------- merged cast (x + 4 weights) + RoPE trig-table fill (tail blocks) -------
__global__ void k_cast(const float* __restrict__ x,  const float* __restrict__ wq,
                       const float* __restrict__ wk, const float* __restrict__ wv,
                       const float* __restrict__ wo, u16* __restrict__ xb,
                       u16* __restrict__ wb, float* __restrict__ tab){
  if (blockIdx.x >= 8192){
    int e = (blockIdx.x - 8192)*256 + threadIdx.x;
    int p = e >> 5, j = e & 31;
    float s, c;
    sincosf((float)p * exp2f(-0.4152410118609203f * (float)j), &s, &c);
    float2 v; v.x = c; v.y = s;
    *(float2*)(tab + e*2) = v;
    return;
  }
  int e = blockIdx.x*1024 + threadIdx.x*4;
  int r = e >> 20;
  const float* s; u16* d; int local;
  if (r < 4){ s = x; d = xb; local = e; }
  else {
    const float* ws[4] = {wq, wk, wv, wo};
    int w = r - 4;
    local = e & 0xFFFFF;
    s = ws[w]; d = wb + ((size_t)w << 20);
  }
  float4 v = *(const float4*)(s + local);
  uint2 t; t.x = cvtpk(v.x, v.y); t.y = cvtpk(v.z, v.w);
  *(uint2*)(d + local) = t;
}

// XCD-chunked bijective block swizzle (nwg % 8 == 0)
__device__ __forceinline__ int xcd_swz(int lin, int nwg){
  return (lin & 7) * (nwg >> 3) + (lin >> 3);
}

// ---------------- GEMM core (R10/R13 verified) ----------------
template<bool SWAP>
__device__ __forceinline__ void gemm_core(const u16* __restrict__ A, const u16* __restrict__ Bw,
                                          u16* S, f32x4 (&acc)[4][4], int m0, int n0){
  const int tid = threadIdx.x, lane = tid & 63, wid = tid >> 6;
  const int wm = (wid >> 1) * 64, wn = (wid & 1) * 64;
  const int ql = lane & 15, lg = lane >> 4;

  #define STAGE_G(buf, k0)                                                       \
    _Pragma("unroll")                                                            \
    for (int i = 0; i < 4; i++){                                                 \
      int L = i*4096 + tid*16;                                                   \
      int r_ = L >> 7;                                                           \
      int orig = ((L >> 4) & 7) ^ (r_ & 7);                                      \
      const u16* src = (orig < 4)                                                \
          ? (A  + (size_t)(m0 + r_)*DM + (k0) + orig*8)                          \
          : (Bw + (size_t)(n0 + r_)*DM + (k0) + (orig - 4)*8);                   \
      gl16(src, (char*)(buf) + L);                                               \
    }

  #define COMPUTE_T(buf)                                                         \
    {                                                                            \
      bf16x8 af[4], bfr[4];                                                      \
      _Pragma("unroll")                                                          \
      for (int mi = 0; mi < 4; mi++){                                            \
        int r = wm + mi*16 + ql;                                                 \
        af[mi] = *(const bf16x8*)((char*)(buf) + r*128 + ((lg*16) ^ ((r & 7) << 4))); \
      }                                                                          \
      _Pragma("unroll")                                                          \
      for (int ni = 0; ni < 4; ni++){                                            \
        int r = wn + ni*16 + ql;                                                 \
        bfr[ni] = *(const bf16x8*)((char*)(buf) + r*128 + ((64 + lg*16) ^ ((r & 7) << 4))); \
      }                                                                          \
      __builtin_amdgcn_s_setprio(1);                                             \
      _Pragma("unroll")                                                          \
      for (int mi = 0; mi < 4; mi++)                                             \
        _Pragma("unroll")                                                        \
        for (int ni = 0; ni < 4; ni++)                                           \
          acc[mi][ni] = SWAP ? mfma16(bfr[ni], af[mi], acc[mi][ni])              \
                             : mfma16(af[mi], bfr[ni], acc[mi][ni]);             \
      __builtin_amdgcn_s_setprio(0);                                             \
    }

  char* b0 = (char*)S;
  char* b1 = (char*)S + 16384;
  char* b2 = (char*)S + 32768;

  STAGE_G(b0, 0);
  STAGE_G(b1, 32);

  #pragma unroll 3
  for (int t = 0; t < 30; t++){
    asm volatile("s_waitcnt vmcnt(4)" ::: "memory");
    __builtin_amdgcn_s_barrier();
    STAGE_G(b2, (t+2)*32);
    COMPUTE_T(b0);
    char* tmp = b0; b0 = b1; b1 = b2; b2 = tmp;
  }
  asm volatile("s_waitcnt vmcnt(4)" ::: "memory");
  __builtin_amdgcn_s_barrier();
  COMPUTE_T(b0);
  { char* tmp = b0; b0 = b1; b1 = b2; b2 = tmp; }
  asm volatile("s_waitcnt vmcnt(0)" ::: "memory");
  __builtin_amdgcn_s_barrier();
  COMPUTE_T(b0);

  #undef STAGE_G
  #undef COMPUTE_T
}

// QKV GEMM (R13 verified): z=0/1 fused-RoPE row-major out; z=2 V transposed.
__global__ __launch_bounds__(256) void k_gemm_qkv(const u16* __restrict__ xb, const u16* __restrict__ Wb,
                                                  u16* __restrict__ Qb, u16* __restrict__ Kb,
                                                  u16* __restrict__ Vt_g, const int* __restrict__ pos,
                                                  const float* __restrict__ tab){
  __shared__ __align__(16) u16 S[3*8192];
  int lin = (int)blockIdx.x + 8*((int)blockIdx.y + 32*(int)blockIdx.z);
  lin = xcd_swz(lin, 768);
  const int bx = lin & 7, by = (lin >> 3) & 31, z = lin >> 8;
  const int m0 = by * 128, n0 = bx * 128;

  const u16* Bw = Wb + ((size_t)z << 20);
  f32x4 acc[4][4] = {};
  gemm_core<true>(xb, Bw, S, acc, m0, n0);
  const int lane = threadIdx.x & 63, wid = threadIdx.x >> 6;
  const int wm0 = m0 + (wid >> 1)*64, wn0 = n0 + (wid & 1)*64;
  const int ql = lane & 15, lg = lane >> 4;

  if (z == 2){
    #pragma unroll
    for (int mi = 0; mi < 4; mi++){
      const int mrow = wm0 + mi*16 + ql;
      const int bq = mrow >> 11, sq = mrow & (SS-1);
      u16* vt = Vt_g + ((size_t)bq*NH*DK)*SS + sq;
      #pragma unroll
      for (int ni = 0; ni < 4; ni++){
        const int nb = wn0 + ni*16 + lg*4;
        #pragma unroll
        for (int r = 0; r < 4; r++)
          vt[(size_t)(nb + r)*SS] = f2bf(acc[mi][ni][r]);
      }
    }
    return;
  }

  u16* C = (z == 0) ? Qb : Kb;
  const float4* tab4 = (const float4*)tab;
  #pragma unroll
  for (int mi = 0; mi < 4; mi++){
    const int mrow = wm0 + mi*16 + ql;
    const int p = pos[mrow & (SS-1)];
    #pragma unroll
    for (int ni = 0; ni < 4; ni++){
      const int nb = wn0 + ni*16 + lg*4;
      float o0 = acc[mi][ni][0], o1 = acc[mi][ni][1];
      float o2 = acc[mi][ni][2], o3 = acc[mi][ni][3];
      int j0 = (nb >> 1) & 31;
      float4 cs = tab4[p*16 + (j0 >> 1)];
      float t0 = o0*cs.x - o1*cs.y, t1 = o0*cs.y + o1*cs.x;
      o0 = t0; o1 = t1;
      t0 = o2*cs.z - o3*cs.w; t1 = o2*cs.w + o3*cs.z;
      o2 = t0; o3 = t1;
      uint2 w; w.x = cvtpk(o0, o1); w.y = cvtpk(o2, o3);
      *(uint2*)(C + (size_t)mrow*DM + nb) = w;
    }
  }
}

__global__ __launch_bounds__(256) void k_gemm_out(const u16* __restrict__ AO, const u16* __restrict__ Wo,
                                                  float* __restrict__ Co){
  __shared__ __align__(16) u16 S[3*8192];
  int lin = (int)blockIdx.x + 8*(int)blockIdx.y;
  lin = xcd_swz(lin, 256);
  const int bx = lin & 7, by = lin >> 3;
  const int m0 = by * 128, n0 = bx * 128;

  f32x4 acc[4][4] = {};
  gemm_core<false>(AO, Wo, S, acc, m0, n0);
  const int lane = threadIdx.x & 63, wid = threadIdx.x >> 6;
  const int wm0 = m0 + (wid >> 1)*64, wn0 = n0 + (wid & 1)*64;
  #pragma unroll
  for (int mi = 0; mi < 4; mi++)
    #pragma unroll
    for (int ni = 0; ni < 4; ni++)
      #pragma unroll
      for (int r = 0; r < 4; r++){
        int m = wm0 + mi*16 + (lane >> 4)*4 + r;
        int n = wn0 + ni*16 + (lane & 15);
        Co[(size_t)m*DM + n] = acc[mi][ni][r];
      }
}

// ---------------- flash attention (R16, verified 47.5us) ----------------
__global__ __launch_bounds__(512, 4) void k_attn(const u16* __restrict__ Q, const u16* __restrict__ K,
                                                 const u16* __restrict__ Vt_g, u16* __restrict__ AO){
  __shared__ __align__(16) u16 Ks[4][64*64];
  __shared__ __align__(16) u16 Vt[4][64*64];
  const int tid = threadIdx.x, lane = tid & 63, wid = tid >> 6;
  const int b = blockIdx.z, h = blockIdx.y;
  const int qb = b ? (15 - (int)blockIdx.x) : (int)blockIdx.x;
  const int strip = wid & 3, g = wid >> 2;
  const int qw = qb*128 + strip*32;
  const size_t base = ((size_t)b*SS)*DM + (size_t)h*DK;
  const size_t vtb  = ((size_t)b*NH + h)*DK*SS;
  const int qi = lane & 31, hh = lane >> 5;
  const int NI = qb + 1;
  const float SC = 0.18033688011112042f;
  const float THR = 8.0f / SC;
  const int qm15 = (qi & 15) << 4;

  const u16* qptr = Q + base + (size_t)(qw + qi)*DM + hh*8;
  bf16x8 qf0 = *(const bf16x8*)(qptr);
  bf16x8 qf1 = *(const bf16x8*)(qptr + 16);
  bf16x8 qf2 = *(const bf16x8*)(qptr + 32);
  bf16x8 qf3 = *(const bf16x8*)(qptr + 48);

  const int L = tid*16;
  const int Lm = ((L >> 3) & 0xF0) ^ ((L >> 6) & 0x10);
  const int A_ = L ^ Lm;
  const int srow = A_ >> 7;
  const int scol = (A_ & 127) >> 1;

  #define STAGE1(bi, t)                                                          \
    {                                                                             \
      const int kn0_ = (t)*64;                                                    \
      gl16(K    + base + (size_t)(kn0_ + srow)*DM + scol, (char*)Ks[bi] + L);      \
      gl16(Vt_g + vtb  + (size_t)srow*SS + kn0_ + scol, (char*)Vt[bi] + L);        \
    }

  STAGE1(0, 0); STAGE1(1, 1);
  if (NI > 1){
    STAGE1(2, 2); STAGE1(3, 3);
    asm volatile("s_waitcnt vmcnt(4)" ::: "memory");
  } else {
    asm volatile("s_waitcnt vmcnt(0)" ::: "memory");
  }
  __builtin_amdgcn_s_barrier();

  f32x16 oacc0 = {}, oacc1 = {};
  float m = -3e38f, lsum = 0.f;

  for (int k = 0; k < NI; k++){
    const int t = 2*k + g;
    const int kv0 = t*64;
    const int bsel = ((k & 1) << 1) | g;
    const char* kb = (const char*)Ks[bsel];
    const char* vb = (const char*)Vt[bsel];

    if (kv0 <= qw + 31){
      #pragma unroll
      for (int H = 0; H < 2; H++){
        f32x16 sf = {};
        __builtin_amdgcn_s_setprio(1);
        #pragma unroll
        for (int kc = 0; kc < 4; kc++){
          const int a0 = (qi*128 + kc*32 + hh*16) ^ qm15;
          bf16x8 kf = *(const bf16x8*)(kb + a0 + H*4096);
          bf16x8 qf = (kc == 0) ? qf0 : (kc == 1) ? qf1 : (kc == 2) ? qf2 : qf3;
          sf = mfma32(kf, qf, sf);
        }
        __builtin_amdgcn_s_setprio(0);

        if (kv0 + 32*H + 31 > qw){
          const int qa = qw + qi;
          #pragma unroll
          for (int r = 0; r < 16; r++){
            int rowoff = 32*H + (r & 3) + 8*(r >> 2) + 4*hh;
            sf[r] = (kv0 + rowoff <= qa) ? sf[r] : -3e38f;
          }
        }

        float t0 = fmaxf(fmaxf(sf[0],  sf[1]),  sf[2]);
        float t1 = fmaxf(fmaxf(sf[3],  sf[4]),  sf[5]);
        float t2 = fmaxf(fmaxf(sf[6],  sf[7]),  sf[8]);
        float t3 = fmaxf(fmaxf(sf[9],  sf[10]), sf[11]);
        float t4 = fmaxf(fmaxf(sf[12], sf[13]), sf[14]);
        float mx = fmaxf(fmaxf(fmaxf(t0, t1), t2), fmaxf(fmaxf(t3, t4), sf[15]));

        if (!__all(mx <= m + THR)){
          mx = fmaxf(mx, __shfl_xor(mx, 32));
          const float mn = fmaxf(m, mx);
          const float alpha = exp2f((m - mn)*SC);
          oacc0 *= alpha; oacc1 *= alpha; lsum *= alpha;
          m = mn;
        }

        const float nms = -m*SC;
        float psum = 0.f;
        #pragma unroll
        for (int r = 0; r < 16; r++){
          sf[r] = exp2f(fmaf(sf[r], SC, nms));
          psum += sf[r];
        }
        lsum += psum;

        __builtin_amdgcn_s_setprio(1);
        #pragma unroll
        for (int TT = 0; TT < 2; TT++){
          u32 w0 = cvtpk(sf[8*TT+0], sf[8*TT+1]);
          u32 w1 = cvtpk(sf[8*TT+2], sf[8*TT+3]);
          u32 w2 = cvtpk(sf[8*TT+4], sf[8*TT+5]);
          u32 w3 = cvtpk(sf[8*TT+6], sf[8*TT+7]);
          asm volatile("v_permlane32_swap_b32 %0, %1" : "+v"(w0), "+v"(w2));
          asm volatile("v_permlane32_swap_b32 %0, %1" : "+v"(w1), "+v"(w3));
          u32 pw[4] = {w0, w1, w2, w3};
          bf16x8 pf;
          __builtin_memcpy(&pf, pw, 16);
          const int av = (qi*128 + (2*H + TT)*32 + hh*16) ^ qm15;
          bf16x8 vfa = *(const bf16x8*)(vb + av);
          bf16x8 vfb = *(const bf16x8*)(vb + av + 4096);
          oacc0 = mfma32(vfa, pf, oacc0);
          oacc1 = mfma32(vfb, pf, oacc1);
        }
        __builtin_amdgcn_s_setprio(0);
      }
    }

    __builtin_amdgcn_s_barrier();
    if (k + 2 < NI){
      STAGE1(((k & 1) << 1) | 0, 2*k + 4);
      STAGE1(((k & 1) << 1) | 1, 2*k + 5);
    }
    if (k + 1 < NI){
      if (k + 2 < NI) asm volatile("s_waitcnt vmcnt(4)" ::: "memory");
      else            asm volatile("s_waitcnt vmcnt(0)" ::: "memory");
      __builtin_amdgcn_s_barrier();
    }
  }
  #undef STAGE1

  __builtin_amdgcn_s_barrier();
  float2* exv  = (float2*)Ks;
  float2* exml = (float2*)((char*)Vt + 16384);
  if (g == 1){
    int idx = (wid - 4)*64 + lane;
    #pragma unroll
    for (int e = 0; e < 8; e++){
      float2 v0; v0.x = oacc0[2*e]; v0.y = oacc0[2*e+1];
      float2 v1; v1.x = oacc1[2*e]; v1.y = oacc1[2*e+1];
      exv[e*256 + idx] = v0;
      exv[(8+e)*256 + idx] = v1;
    }
    float2 ml; ml.x = m; ml.y = lsum;
    exml[idx] = ml;
  }
  __builtin_amdgcn_s_barrier();
  if (g == 1) return;

  {
    int idx = wid*64 + lane;
    float2 ml = exml[idx];
    const float mm = fmaxf(m, ml.x);
    const float aA = exp2f((m - mm)*SC);
    const float aB = exp2f((ml.x - mm)*SC);
    lsum = lsum*aA + ml.y*aB;
    #pragma unroll
    for (int e = 0; e < 8; e++){
      float2 v0 = exv[e*256 + idx];
      float2 v1 = exv[(8+e)*256 + idx];
      oacc0[2*e]   = oacc0[2*e]*aA   + v0.x*aB;
      oacc0[2*e+1] = oacc0[2*e+1]*aA + v0.y*aB;
      oacc1[2*e]   = oacc1[2*e]*aA   + v1.x*aB;
      oacc1[2*e+1] = oacc1[2*e+1]*aA + v1.y*aB;
    }
  }
  lsum += __shfl_xor(lsum, 32);
  const float rl = 1.0f / lsum;

  char* sc = (char*)Vt[0] + wid*4096;
  #pragma unroll
  for (int w = 0; w < 8; w++){
    const int pb = (w & 1)*2 + (w >> 1)*8;
    const int db0 = 4*hh + pb;
    const int db1 = 32 + 4*hh + pb;
    *(u32*)(sc + ((qi*128 + db0*2) ^ ((qi & 7) << 4))) = cvtpk(oacc0[2*w]*rl, oacc0[2*w+1]*rl);
    *(u32*)(sc + ((qi*128 + db1*2) ^ ((qi & 7) << 4))) = cvtpk(oacc1[2*w]*rl, oacc1[2*w+1]*rl);
  }
  #pragma unroll
  for (int pass = 0; pass < 4; pass++){
    int qr = pass*8 + (lane >> 3);
    int d0 = (lane & 7)*8;
    bf16x8 row = *(const bf16x8*)(sc + ((qr*128 + d0*2) ^ ((qr & 7) << 4)));
    *(bf16x8*)(AO + base + (size_t)(qw + qr)*DM + d0) = row;
  }
}

// ---------------- launch ----------------
extern "C" void kernel_launch(void* const* d_in, const int* in_sizes, int n_in,
                              void* d_out, int out_size, void* d_ws, size_t ws_size,
                              hipStream_t stream){
  const float* x   = (const float*)d_in[0];
  const float* Wq  = (const float*)d_in[1];
  const float* Wk  = (const float*)d_in[2];
  const float* Wv  = (const float*)d_in[3];
  const float* Wo  = (const float*)d_in[4];
  const int*   pos = (const int*)d_in[5];
  float* out = (float*)d_out;

  const size_t NEED = ((size_t)41 << 20);
  if (ws_size < NEED){
    hipMemsetAsync(d_out, 0x7f, (size_t)out_size * sizeof(float), stream);
    return;
  }

  char* ws = (char*)d_ws;
  u16* xb   = (u16*)(ws);
  u16* Wb   = (u16*)(ws + ((size_t)8  << 20));
  u16* Qb   = (u16*)(ws + ((size_t)16 << 20));
  u16* Kb   = (u16*)(ws + ((size_t)24 << 20));
  u16* Vt   = (u16*)(ws + ((size_t)32 << 20));
  float* tab = (float*)(ws + ((size_t)40 << 20));
  u16* AO = xb;

  k_cast<<<8448, 256, 0, stream>>>(x, Wq, Wk, Wv, Wo, xb, Wb, tab);
  k_gemm_qkv<<<dim3(8, 32, 3), 256, 0, stream>>>(xb, Wb, Qb, Kb, Vt, pos, tab);
  k_attn<<<dim3(16, 16, 2), 512, 0, stream>>>(Qb, Kb, Vt, AO);
  k_gemm_out<<<dim3(8, 32), 256, 0, stream>>>(AO, Wb + ((size_t)3 << 20), out);
}

// Round 19
// 104.572 us; speedup vs baseline: 1.0565x; 1.0455x over previous
//
#include <hip/hip_runtime.h>

#define DM 1024
#define NH 16
#define DK 64
#define BB 2
#define SS 2048

typedef unsigned short u16;
typedef unsigned int   u32;
typedef __bf16 bf16x8 __attribute__((ext_vector_type(8)));
typedef float  f32x4  __attribute__((ext_vector_type(4)));
typedef float  f32x16 __attribute__((ext_vector_type(16)));

__device__ __forceinline__ u16 f2bf(float f){
  u32 u = __float_as_uint(f);
  u32 r = (u + 0x7FFFu + ((u >> 16) & 1u)) >> 16;   // RNE
  return (u16)r;
}
__device__ __forceinline__ float bf2f(u16 v){ return __uint_as_float(((u32)v) << 16); }

__device__ __forceinline__ u32 cvtpk(float lo, float hi){
  u32 r;
  asm volatile("v_cvt_pk_bf16_f32 %0, %1, %2" : "=v"(r) : "v"(lo), "v"(hi));
  return r;
}

__device__ __forceinline__ void gl16(const void* g, void* l){
  __builtin_amdgcn_global_load_lds((const __attribute__((address_space(1))) u32*)g,
                                   (__attribute__((address_space(3))) u32*)l, 16, 0, 0);
}
__device__ __forceinline__ f32x4 mfma16(bf16x8 a, bf16x8 b, f32x4 c){
  return __builtin_amdgcn_mfma_f32_16x16x32_bf16(a, b, c, 0, 0, 0);
}
__device__ __forceinline__ f32x16 mfma32(bf16x8 a, bf16x8 b, f32x16 c){
  return __builtin_amdgcn_mfma_f32_32x32x16_bf16(a, b, c, 0, 0, 0);
}

// ------- merged cast (x + 4 weights) + RoPE trig-table fill (tail blocks) -------
__global__ void k_cast(const float* __restrict__ x,  const float* __restrict__ wq,
                       const float* __restrict__ wk, const float* __restrict__ wv,
                       const float* __restrict__ wo, u16* __restrict__ xb,
                       u16* __restrict__ wb, float* __restrict__ tab){
  if (blockIdx.x >= 8192){
    int e = (blockIdx.x - 8192)*256 + threadIdx.x;
    int p = e >> 5, j = e & 31;
    float s, c;
    sincosf((float)p * exp2f(-0.4152410118609203f * (float)j), &s, &c);
    float2 v; v.x = c; v.y = s;
    *(float2*)(tab + e*2) = v;
    return;
  }
  int e = blockIdx.x*1024 + threadIdx.x*4;
  int r = e >> 20;
  const float* s; u16* d; int local;
  if (r < 4){ s = x; d = xb; local = e; }
  else {
    const float* ws[4] = {wq, wk, wv, wo};
    int w = r - 4;
    local = e & 0xFFFFF;
    s = ws[w]; d = wb + ((size_t)w << 20);
  }
  float4 v = *(const float4*)(s + local);
  uint2 t; t.x = cvtpk(v.x, v.y); t.y = cvtpk(v.z, v.w);
  *(uint2*)(d + local) = t;
}

// XCD-chunked bijective block swizzle (nwg % 8 == 0)
__device__ __forceinline__ int xcd_swz(int lin, int nwg){
  return (lin & 7) * (nwg >> 3) + (lin >> 3);
}

// ---------------- GEMM core R19: 512 threads / 8 waves per block ----------------
// Same 128x128 tile, BK=32, triple-buffer, counted vmcnt (R10-verified skeleton),
// 8-slot XOR swizzle (R9-verified, conflicts=0). Each wave owns a 32x64 sub-tile
// (acc[2][4], 8 mfma16/interval). Staging: 2 gl16/thread -> vmcnt counts 4 -> 2.
// Occupancy: 3 blocks x 8 waves = 24 waves/CU (was 12) - the latency-bound fix.
template<bool SWAP>
__device__ __forceinline__ void gemm_core(const u16* __restrict__ A, const u16* __restrict__ Bw,
                                          u16* S, f32x4 (&acc)[2][4], int m0, int n0){
  const int tid = threadIdx.x, lane = tid & 63, wid = tid >> 6;
  const int wm = (wid >> 1) * 32, wn = (wid & 1) * 64;
  const int ql = lane & 15, lg = lane >> 4;

  #define STAGE_G(buf, k0)                                                       \
    _Pragma("unroll")                                                            \
    for (int i = 0; i < 2; i++){                                                 \
      int L = i*8192 + tid*16;                                                   \
      int r_ = L >> 7;                                                           \
      int orig = ((L >> 4) & 7) ^ (r_ & 7);                                      \
      const u16* src = (orig < 4)                                                \
          ? (A  + (size_t)(m0 + r_)*DM + (k0) + orig*8)                          \
          : (Bw + (size_t)(n0 + r_)*DM + (k0) + (orig - 4)*8);                   \
      gl16(src, (char*)(buf) + L);                                               \
    }

  #define COMPUTE_T(buf)                                                         \
    {                                                                            \
      bf16x8 af[2], bfr[4];                                                      \
      _Pragma("unroll")                                                          \
      for (int mi = 0; mi < 2; mi++){                                            \
        int r = wm + mi*16 + ql;                                                 \
        af[mi] = *(const bf16x8*)((char*)(buf) + r*128 + ((lg*16) ^ ((r & 7) << 4))); \
      }                                                                          \
      _Pragma("unroll")                                                          \
      for (int ni = 0; ni < 4; ni++){                                            \
        int r = wn + ni*16 + ql;                                                 \
        bfr[ni] = *(const bf16x8*)((char*)(buf) + r*128 + ((64 + lg*16) ^ ((r & 7) << 4))); \
      }                                                                          \
      __builtin_amdgcn_s_setprio(1);                                             \
      _Pragma("unroll")                                                          \
      for (int mi = 0; mi < 2; mi++)                                             \
        _Pragma("unroll")                                                        \
        for (int ni = 0; ni < 4; ni++)                                           \
          acc[mi][ni] = SWAP ? mfma16(bfr[ni], af[mi], acc[mi][ni])              \
                             : mfma16(af[mi], bfr[ni], acc[mi][ni]);             \
      __builtin_amdgcn_s_setprio(0);                                             \
    }

  char* b0 = (char*)S;
  char* b1 = (char*)S + 16384;
  char* b2 = (char*)S + 32768;

  STAGE_G(b0, 0);
  STAGE_G(b1, 32);

  #pragma unroll 3
  for (int t = 0; t < 30; t++){
    asm volatile("s_waitcnt vmcnt(2)" ::: "memory");   // stage(t) done, (t+1) in flight
    __builtin_amdgcn_s_barrier();
    STAGE_G(b2, (t+2)*32);                             // depth-2 prefetch
    COMPUTE_T(b0);
    char* tmp = b0; b0 = b1; b1 = b2; b2 = tmp;
  }
  asm volatile("s_waitcnt vmcnt(2)" ::: "memory");
  __builtin_amdgcn_s_barrier();
  COMPUTE_T(b0);
  { char* tmp = b0; b0 = b1; b1 = b2; b2 = tmp; }
  asm volatile("s_waitcnt vmcnt(0)" ::: "memory");
  __builtin_amdgcn_s_barrier();
  COMPUTE_T(b0);

  #undef STAGE_G
  #undef COMPUTE_T
}

// QKV GEMM: z=0/1 fused-RoPE row-major out; z=2 V transposed (R13-verified mappings;
// only wave geometry changed: wm0 stride 32, mi<2).
__global__ __launch_bounds__(512, 6) void k_gemm_qkv(const u16* __restrict__ xb, const u16* __restrict__ Wb,
                                                     u16* __restrict__ Qb, u16* __restrict__ Kb,
                                                     u16* __restrict__ Vt_g, const int* __restrict__ pos,
                                                     const float* __restrict__ tab){
  __shared__ __align__(16) u16 S[3*8192];
  int lin = (int)blockIdx.x + 8*((int)blockIdx.y + 32*(int)blockIdx.z);
  lin = xcd_swz(lin, 768);
  const int bx = lin & 7, by = (lin >> 3) & 31, z = lin >> 8;
  const int m0 = by * 128, n0 = bx * 128;

  const u16* Bw = Wb + ((size_t)z << 20);
  f32x4 acc[2][4] = {};
  gemm_core<true>(xb, Bw, S, acc, m0, n0);
  const int lane = threadIdx.x & 63, wid = threadIdx.x >> 6;
  const int wm0 = m0 + (wid >> 1)*32, wn0 = n0 + (wid & 1)*64;
  const int ql = lane & 15, lg = lane >> 4;

  if (z == 2){
    #pragma unroll
    for (int mi = 0; mi < 2; mi++){
      const int mrow = wm0 + mi*16 + ql;
      const int bq = mrow >> 11, sq = mrow & (SS-1);
      u16* vt = Vt_g + ((size_t)bq*NH*DK)*SS + sq;
      #pragma unroll
      for (int ni = 0; ni < 4; ni++){
        const int nb = wn0 + ni*16 + lg*4;
        #pragma unroll
        for (int r = 0; r < 4; r++)
          vt[(size_t)(nb + r)*SS] = f2bf(acc[mi][ni][r]);
      }
    }
    return;
  }

  u16* C = (z == 0) ? Qb : Kb;
  const float4* tab4 = (const float4*)tab;
  #pragma unroll
  for (int mi = 0; mi < 2; mi++){
    const int mrow = wm0 + mi*16 + ql;
    const int p = pos[mrow & (SS-1)];
    #pragma unroll
    for (int ni = 0; ni < 4; ni++){
      const int nb = wn0 + ni*16 + lg*4;
      float o0 = acc[mi][ni][0], o1 = acc[mi][ni][1];
      float o2 = acc[mi][ni][2], o3 = acc[mi][ni][3];
      int j0 = (nb >> 1) & 31;
      float4 cs = tab4[p*16 + (j0 >> 1)];
      float t0 = o0*cs.x - o1*cs.y, t1 = o0*cs.y + o1*cs.x;
      o0 = t0; o1 = t1;
      t0 = o2*cs.z - o3*cs.w; t1 = o2*cs.w + o3*cs.z;
      o2 = t0; o3 = t1;
      uint2 w; w.x = cvtpk(o0, o1); w.y = cvtpk(o2, o3);
      *(uint2*)(C + (size_t)mrow*DM + nb) = w;
    }
  }
}

__global__ __launch_bounds__(512, 6) void k_gemm_out(const u16* __restrict__ AO, const u16* __restrict__ Wo,
                                                     float* __restrict__ Co){
  __shared__ __align__(16) u16 S[3*8192];
  int lin = (int)blockIdx.x + 8*(int)blockIdx.y;
  lin = xcd_swz(lin, 256);
  const int bx = lin & 7, by = lin >> 3;
  const int m0 = by * 128, n0 = bx * 128;

  f32x4 acc[2][4] = {};
  gemm_core<false>(AO, Wo, S, acc, m0, n0);
  const int lane = threadIdx.x & 63, wid = threadIdx.x >> 6;
  const int wm0 = m0 + (wid >> 1)*32, wn0 = n0 + (wid & 1)*64;
  #pragma unroll
  for (int mi = 0; mi < 2; mi++)
    #pragma unroll
    for (int ni = 0; ni < 4; ni++)
      #pragma unroll
      for (int r = 0; r < 4; r++){
        int m = wm0 + mi*16 + (lane >> 4)*4 + r;
        int n = wn0 + ni*16 + (lane & 15);
        Co[(size_t)m*DM + n] = acc[mi][ni][r];
      }
}

// ---------------- flash attention (R16, verified 47.5us) ----------------
__global__ __launch_bounds__(512, 4) void k_attn(const u16* __restrict__ Q, const u16* __restrict__ K,
                                                 const u16* __restrict__ Vt_g, u16* __restrict__ AO){
  __shared__ __align__(16) u16 Ks[4][64*64];
  __shared__ __align__(16) u16 Vt[4][64*64];
  const int tid = threadIdx.x, lane = tid & 63, wid = tid >> 6;
  const int b = blockIdx.z, h = blockIdx.y;
  const int qb = b ? (15 - (int)blockIdx.x) : (int)blockIdx.x;
  const int strip = wid & 3, g = wid >> 2;
  const int qw = qb*128 + strip*32;
  const size_t base = ((size_t)b*SS)*DM + (size_t)h*DK;
  const size_t vtb  = ((size_t)b*NH + h)*DK*SS;
  const int qi = lane & 31, hh = lane >> 5;
  const int NI = qb + 1;
  const float SC = 0.18033688011112042f;
  const float THR = 8.0f / SC;
  const int qm15 = (qi & 15) << 4;

  const u16* qptr = Q + base + (size_t)(qw + qi)*DM + hh*8;
  bf16x8 qf0 = *(const bf16x8*)(qptr);
  bf16x8 qf1 = *(const bf16x8*)(qptr + 16);
  bf16x8 qf2 = *(const bf16x8*)(qptr + 32);
  bf16x8 qf3 = *(const bf16x8*)(qptr + 48);

  const int L = tid*16;
  const int Lm = ((L >> 3) & 0xF0) ^ ((L >> 6) & 0x10);
  const int A_ = L ^ Lm;
  const int srow = A_ >> 7;
  const int scol = (A_ & 127) >> 1;

  #define STAGE1(bi, t)                                                          \
    {                                                                             \
      const int kn0_ = (t)*64;                                                    \
      gl16(K    + base + (size_t)(kn0_ + srow)*DM + scol, (char*)Ks[bi] + L);      \
      gl16(Vt_g + vtb  + (size_t)srow*SS + kn0_ + scol, (char*)Vt[bi] + L);        \
    }

  STAGE1(0, 0); STAGE1(1, 1);
  if (NI > 1){
    STAGE1(2, 2); STAGE1(3, 3);
    asm volatile("s_waitcnt vmcnt(4)" ::: "memory");
  } else {
    asm volatile("s_waitcnt vmcnt(0)" ::: "memory");
  }
  __builtin_amdgcn_s_barrier();

  f32x16 oacc0 = {}, oacc1 = {};
  float m = -3e38f, lsum = 0.f;

  for (int k = 0; k < NI; k++){
    const int t = 2*k + g;
    const int kv0 = t*64;
    const int bsel = ((k & 1) << 1) | g;
    const char* kb = (const char*)Ks[bsel];
    const char* vb = (const char*)Vt[bsel];

    if (kv0 <= qw + 31){
      #pragma unroll
      for (int H = 0; H < 2; H++){
        f32x16 sf = {};
        __builtin_amdgcn_s_setprio(1);
        #pragma unroll
        for (int kc = 0; kc < 4; kc++){
          const int a0 = (qi*128 + kc*32 + hh*16) ^ qm15;
          bf16x8 kf = *(const bf16x8*)(kb + a0 + H*4096);
          bf16x8 qf = (kc == 0) ? qf0 : (kc == 1) ? qf1 : (kc == 2) ? qf2 : qf3;
          sf = mfma32(kf, qf, sf);
        }
        __builtin_amdgcn_s_setprio(0);

        if (kv0 + 32*H + 31 > qw){
          const int qa = qw + qi;
          #pragma unroll
          for (int r = 0; r < 16; r++){
            int rowoff = 32*H + (r & 3) + 8*(r >> 2) + 4*hh;
            sf[r] = (kv0 + rowoff <= qa) ? sf[r] : -3e38f;
          }
        }

        float t0 = fmaxf(fmaxf(sf[0],  sf[1]),  sf[2]);
        float t1 = fmaxf(fmaxf(sf[3],  sf[4]),  sf[5]);
        float t2 = fmaxf(fmaxf(sf[6],  sf[7]),  sf[8]);
        float t3 = fmaxf(fmaxf(sf[9],  sf[10]), sf[11]);
        float t4 = fmaxf(fmaxf(sf[12], sf[13]), sf[14]);
        float mx = fmaxf(fmaxf(fmaxf(t0, t1), t2), fmaxf(fmaxf(t3, t4), sf[15]));

        if (!__all(mx <= m + THR)){
          mx = fmaxf(mx, __shfl_xor(mx, 32));
          const float mn = fmaxf(m, mx);
          const float alpha = exp2f((m - mn)*SC);
          oacc0 *= alpha; oacc1 *= alpha; lsum *= alpha;
          m = mn;
        }

        const float nms = -m*SC;
        float psum = 0.f;
        #pragma unroll
        for (int r = 0; r < 16; r++){
          sf[r] = exp2f(fmaf(sf[r], SC, nms));
          psum += sf[r];
        }
        lsum += psum;

        __builtin_amdgcn_s_setprio(1);
        #pragma unroll
        for (int TT = 0; TT < 2; TT++){
          u32 w0 = cvtpk(sf[8*TT+0], sf[8*TT+1]);
          u32 w1 = cvtpk(sf[8*TT+2], sf[8*TT+3]);
          u32 w2 = cvtpk(sf[8*TT+4], sf[8*TT+5]);
          u32 w3 = cvtpk(sf[8*TT+6], sf[8*TT+7]);
          asm volatile("v_permlane32_swap_b32 %0, %1" : "+v"(w0), "+v"(w2));
          asm volatile("v_permlane32_swap_b32 %0, %1" : "+v"(w1), "+v"(w3));
          u32 pw[4] = {w0, w1, w2, w3};
          bf16x8 pf;
          __builtin_memcpy(&pf, pw, 16);
          const int av = (qi*128 + (2*H + TT)*32 + hh*16) ^ qm15;
          bf16x8 vfa = *(const bf16x8*)(vb + av);
          bf16x8 vfb = *(const bf16x8*)(vb + av + 4096);
          oacc0 = mfma32(vfa, pf, oacc0);
          oacc1 = mfma32(vfb, pf, oacc1);
        }
        __builtin_amdgcn_s_setprio(0);
      }
    }

    __builtin_amdgcn_s_barrier();
    if (k + 2 < NI){
      STAGE1(((k & 1) << 1) | 0, 2*k + 4);
      STAGE1(((k & 1) << 1) | 1, 2*k + 5);
    }
    if (k + 1 < NI){
      if (k + 2 < NI) asm volatile("s_waitcnt vmcnt(4)" ::: "memory");
      else            asm volatile("s_waitcnt vmcnt(0)" ::: "memory");
      __builtin_amdgcn_s_barrier();
    }
  }
  #undef STAGE1

  __builtin_amdgcn_s_barrier();
  float2* exv  = (float2*)Ks;
  float2* exml = (float2*)((char*)Vt + 16384);
  if (g == 1){
    int idx = (wid - 4)*64 + lane;
    #pragma unroll
    for (int e = 0; e < 8; e++){
      float2 v0; v0.x = oacc0[2*e]; v0.y = oacc0[2*e+1];
      float2 v1; v1.x = oacc1[2*e]; v1.y = oacc1[2*e+1];
      exv[e*256 + idx] = v0;
      exv[(8+e)*256 + idx] = v1;
    }
    float2 ml; ml.x = m; ml.y = lsum;
    exml[idx] = ml;
  }
  __builtin_amdgcn_s_barrier();
  if (g == 1) return;

  {
    int idx = wid*64 + lane;
    float2 ml = exml[idx];
    const float mm = fmaxf(m, ml.x);
    const float aA = exp2f((m - mm)*SC);
    const float aB = exp2f((ml.x - mm)*SC);
    lsum = lsum*aA + ml.y*aB;
    #pragma unroll
    for (int e = 0; e < 8; e++){
      float2 v0 = exv[e*256 + idx];
      float2 v1 = exv[(8+e)*256 + idx];
      oacc0[2*e]   = oacc0[2*e]*aA   + v0.x*aB;
      oacc0[2*e+1] = oacc0[2*e+1]*aA + v0.y*aB;
      oacc1[2*e]   = oacc1[2*e]*aA   + v1.x*aB;
      oacc1[2*e+1] = oacc1[2*e+1]*aA + v1.y*aB;
    }
  }
  lsum += __shfl_xor(lsum, 32);
  const float rl = 1.0f / lsum;

  char* sc = (char*)Vt[0] + wid*4096;
  #pragma unroll
  for (int w = 0; w < 8; w++){
    const int pb = (w & 1)*2 + (w >> 1)*8;
    const int db0 = 4*hh + pb;
    const int db1 = 32 + 4*hh + pb;
    *(u32*)(sc + ((qi*128 + db0*2) ^ ((qi & 7) << 4))) = cvtpk(oacc0[2*w]*rl, oacc0[2*w+1]*rl);
    *(u32*)(sc + ((qi*128 + db1*2) ^ ((qi & 7) << 4))) = cvtpk(oacc1[2*w]*rl, oacc1[2*w+1]*rl);
  }
  #pragma unroll
  for (int pass = 0; pass < 4; pass++){
    int qr = pass*8 + (lane >> 3);
    int d0 = (lane & 7)*8;
    bf16x8 row = *(const bf16x8*)(sc + ((qr*128 + d0*2) ^ ((qr & 7) << 4)));
    *(bf16x8*)(AO + base + (size_t)(qw + qr)*DM + d0) = row;
  }
}

// ---------------- launch ----------------
extern "C" void kernel_launch(void* const* d_in, const int* in_sizes, int n_in,
                              void* d_out, int out_size, void* d_ws, size_t ws_size,
                              hipStream_t stream){
  const float* x   = (const float*)d_in[0];
  const float* Wq  = (const float*)d_in[1];
  const float* Wk  = (const float*)d_in[2];
  const float* Wv  = (const float*)d_in[3];
  const float* Wo  = (const float*)d_in[4];
  const int*   pos = (const int*)d_in[5];
  float* out = (float*)d_out;

  const size_t NEED = ((size_t)41 << 20);
  if (ws_size < NEED){
    hipMemsetAsync(d_out, 0x7f, (size_t)out_size * sizeof(float), stream);
    return;
  }

  char* ws = (char*)d_ws;
  u16* xb   = (u16*)(ws);
  u16* Wb   = (u16*)(ws + ((size_t)8  << 20));
  u16* Qb   = (u16*)(ws + ((size_t)16 << 20));
  u16* Kb   = (u16*)(ws + ((size_t)24 << 20));
  u16* Vt   = (u16*)(ws + ((size_t)32 << 20));
  float* tab = (float*)(ws + ((size_t)40 << 20));
  u16* AO = xb;

  k_cast<<<8448, 256, 0, stream>>>(x, Wq, Wk, Wv, Wo, xb, Wb, tab);
  k_gemm_qkv<<<dim3(8, 32, 3), 512, 0, stream>>>(xb, Wb, Qb, Kb, Vt, pos, tab);
  k_attn<<<dim3(16, 16, 2), 512, 0, stream>>>(Qb, Kb, Vt, AO);
  k_gemm_out<<<dim3(8, 32), 512, 0, stream>>>(AO, Wb + ((size_t)3 << 20), out);
}